// Round 10
// baseline (84.096 us; speedup 1.0000x reference)
//
#include <hip/hip_runtime.h>
#include <hip/hip_cooperative_groups.h>

namespace cg = cooperative_groups;

// EKV nonlinear conv2d, MI355X.
// out[b,co,h,w] = alpha * sum_{cin,i,j} sp((v-th)*inv)^2 - sp((v-th-0.1)*inv)^2
// log2-domain: e1 = 2^(v*s) * 2^(-th*s), e2 = e1*KF,
//   term = ln2^2 * (log2(1+e1)^2 - log2(1+e2)^2)
//
// v11 vs 24.1us v10: compute is <2us; remaining time is launch/structure
// overhead (two serialized launches + latency-bound rowmax + prologue
// chains). Fuse into ONE cooperative kernel:
//   phase 1: blocks 0..255 compute the (b,cin)-plane window-max table wg
//            (exact v10 rowmax body; other 256 blocks fall through).
//   grid.sync()  (hipLaunchCooperativeKernel, 512 blocks = 2/CU resident)
//   phase 2: all 512 blocks run the v10 main body (task-swizzled).
// Kept from v10: register/shuffle metadata (lane l owns cin l: 9 theta, tap
// mask tlm, q[] in regs; __shfl per plane), per-tap skip at DELTA=5/S
// (worst-case skipped-term total 3.2e-4 < 7.47e-4 threshold), dead-row load
// elimination, register 3-row window + direct edge scalars (pad selected
// before exp2), depth-2 ping-pong pipeline, XCD-bijective swizzle, zero LDS
// / zero barriers in the main body.

constexpr int CIN  = 64;
constexpr int COUT = 128;
constexpr int HW   = 32;
constexpr int PIX  = HW * HW;       // 1024

constexpr float S     = 19.235933878519512f;     // (1/0.075) * log2(e)
constexpr float KF    = 0.26359713811572677f;    // exp(-0.1/0.075)
constexpr float OSC   = 2.7025482032899376e-4f;  // alpha * ln2^2
constexpr float DELTA = 0.2599401f;              // 5/S rounded UP (conservative)

__global__ __launch_bounds__(256, 4)
void ekv_fused(const float* __restrict__ V, const float* __restrict__ Th,
               float* __restrict__ wg, float* __restrict__ Out)
{
    const int t = threadIdx.x;
    const int g = blockIdx.x;

    __shared__ float rmax[32];

    // ---- phase 1: blocks 0..255 = one (b,cin) plane each -> wg table ----
    if (g < 4 * CIN) {
        const float4 v4 = reinterpret_cast<const float4*>(V + (size_t)g * PIX)[t];
        float m = fmaxf(fmaxf(v4.x, v4.y), fmaxf(v4.z, v4.w));
        m = fmaxf(m, __shfl_xor(m, 1));         // reduce 8 lanes of one row
        m = fmaxf(m, __shfl_xor(m, 2));
        m = fmaxf(m, __shfl_xor(m, 4));
        if ((t & 7) == 0) rmax[t >> 3] = m;
        __syncthreads();
        if (t < 4) {
            float wm = 0.0f;                    // halo pixels are v=0 -> e=1
            #pragma unroll
            for (int rr = 0; rr < 10; ++rr) {
                const int r = 8 * t - 1 + rr;
                if (r >= 0 && r < 32) wm = fmaxf(wm, rmax[r]);
            }
            wg[g * 4 + t] = wm;                 // wg[(b*CIN+cin)*4 + w]
        }
    }

    cg::this_grid().sync();                     // wg visible to all blocks

    // ---- phase 2: main. XCD-bijective swizzle (nwg=512): XCD x gets a
    // contiguous 64-task chunk (one b, 64 consecutive co) -> L2-resident.
    const int task = ((g & 7) << 6) | (g >> 3);
    const int co   = task & (COUT - 1);
    const int b    = task >> 7;
    const int w    = t >> 6;                    // wave = window 0..3
    const int lane = t & 63;

    const float* vbase = V  + (size_t)b  * CIN * PIX;
    const float* thp   = Th + (size_t)co * (CIN * 9);

    // register prologue: lane l = cin l
    float th[9];
    #pragma unroll
    for (int k = 0; k < 9; ++k) th[k] = thp[lane * 9 + k];
    const float wgv = wg[(size_t)(b * CIN + lane) * 4 + w];
    const float lim = wgv + DELTA;
    unsigned tlm = 0u;                          // bit 3i+j: tap (i,j) live
    #pragma unroll
    for (int k = 0; k < 9; ++k) if (th[k] <= lim) tlm |= (1u << k);
    float q[9];
    #pragma unroll
    for (int k = 0; k < 9; ++k) q[k] = __builtin_amdgcn_exp2f(-th[k] * S);
    unsigned long long mask = __ballot(tlm != 0u);   // this wave's active cin

    const int lr = lane >> 3;                   // 0..7
    const int lc = (lane & 7) * 4;              // 0..28
    const int r   = 8 * w + lr;                 // own output/input row
    const int rm1 = (r - 1 < 0)  ? 0  : r - 1;  // clamped load rows
    const int rp1 = (r + 1 > 31) ? 31 : r + 1;
    const bool okA = (r - 1) >= 0;              // row above exists?
    const bool okC = (r + 1) <= 31;             // row below exists?
    const bool isL = (lane & 7) == 0;           // left image edge group
    const bool isR = (lane & 7) == 7;           // right image edge group
    const int  lcl = isL ? 0 : lc - 1;          // clamped edge-scalar cols
    const int  lcr = isR ? 31 : lc + 4;

    float acc0 = 0.f, acc1 = 0.f, acc2 = 0.f, acc3 = 0.f;

    auto pop = [&]() -> int {
        if (!mask) return -1;
        const int c = (int)__builtin_ctzll(mask); mask &= mask - 1; return c;
    };
    // load only live rows (liveness via wave-uniform shuffle of tlm)
    auto issue = [&](int cin, float4& A, float4& B, float4& C,
                     float2& eA, float2& eB, float2& eC) {
        const unsigned tc = (unsigned)__shfl((int)tlm, cin);
        const float* src = vbase + cin * PIX;
        if (tc & 7u) {
            const float* ra = src + rm1 * HW;
            A = *reinterpret_cast<const float4*>(ra + lc);
            eA.x = ra[lcl]; eA.y = ra[lcr];
        }
        if (tc & 56u) {
            const float* rb = src + r * HW;
            B = *reinterpret_cast<const float4*>(rb + lc);
            eB.x = rb[lcl]; eB.y = rb[lcr];
        }
        if (tc & 448u) {
            const float* rc = src + rp1 * HW;
            C = *reinterpret_cast<const float4*>(rc + lc);
            eC.x = rc[lcl]; eC.y = rc[lcr];
        }
    };
    // row -> 6 exp'd values; pad (v=0 -> e=1) selected BEFORE exp2
    auto rowv = [&](const float4& x, const float2& e, bool ok, float* vals) {
        vals[0] = __builtin_amdgcn_exp2f(((ok && !isL) ? e.x : 0.f) * S);
        vals[1] = __builtin_amdgcn_exp2f((ok ? x.x : 0.f) * S);
        vals[2] = __builtin_amdgcn_exp2f((ok ? x.y : 0.f) * S);
        vals[3] = __builtin_amdgcn_exp2f((ok ? x.z : 0.f) * S);
        vals[4] = __builtin_amdgcn_exp2f((ok ? x.w : 0.f) * S);
        vals[5] = __builtin_amdgcn_exp2f(((ok && !isR) ? e.y : 0.f) * S);
    };
    auto compute = [&](int cin, const float4& A, const float4& B, const float4& C,
                       const float2& eA, const float2& eB, const float2& eC) {
        const unsigned tc = (unsigned)__shfl((int)tlm, cin);
        float qc[9];
        #pragma unroll
        for (int k = 0; k < 9; ++k) qc[k] = __shfl(q[k], cin);
        #pragma unroll
        for (int i = 0; i < 3; ++i) {
            if (!((tc >> (3 * i)) & 7u)) continue;        // tap-row dead
            float vals[6];
            if      (i == 0) rowv(A, eA, okA, vals);
            else if (i == 1) rowv(B, eB, true, vals);
            else             rowv(C, eC, okC, vals);
            #pragma unroll
            for (int j = 0; j < 3; ++j) {
                if (!((tc >> (3 * i + j)) & 1u)) continue; // tap dead
                const float qa = qc[3 * i + j];
                const float qb = qa * KF;
                #pragma unroll
                for (int k = 0; k < 4; ++k) {
                    const float x1 = __builtin_fmaf(vals[k + j], qa, 1.0f);
                    const float x2 = __builtin_fmaf(vals[k + j], qb, 1.0f);
                    const float l1 = __builtin_amdgcn_logf(x1);   // log2
                    const float l2 = __builtin_amdgcn_logf(x2);
                    const float su = l1 + l2, di = l1 - l2;       // l1^2-l2^2
                    if      (k == 0) acc0 = __builtin_fmaf(su, di, acc0);
                    else if (k == 1) acc1 = __builtin_fmaf(su, di, acc1);
                    else if (k == 2) acc2 = __builtin_fmaf(su, di, acc2);
                    else             acc3 = __builtin_fmaf(su, di, acc3);
                }
            }
        }
    };

    // depth-2 pipeline, ping-pong register sets A/B (loads issued 2 planes ahead)
    {
        float4 aA = make_float4(0.f,0.f,0.f,0.f), bA = aA, cA = aA;
        float4 aB = aA, bB = aA, cB = aA;
        float2 eaA = make_float2(0.f,0.f), ebA = eaA, ecA = eaA;
        float2 eaB = eaA, ebB = eaA, ecB = eaA;
        int q0 = pop();
        if (q0 >= 0) {
            issue(q0, aA, bA, cA, eaA, ebA, ecA);
            int q1 = pop();
            if (q1 >= 0) issue(q1, aB, bB, cB, eaB, ebB, ecB);
            for (;;) {
                // EVEN: current plane q0 in set A; 2-ahead issued into dead A regs
                {
                    const float4 xa = aA, xb = bA, xc = cA;
                    const float2 ya = eaA, yb = ebA, yc = ecA;
                    int q2 = (q1 >= 0) ? pop() : -1;
                    if (q2 >= 0) issue(q2, aA, bA, cA, eaA, ebA, ecA);
                    compute(q0, xa, xb, xc, ya, yb, yc);
                    if (q1 < 0) break;
                    q0 = q2;
                }
                // ODD: current plane q1 in set B
                {
                    const float4 xa = aB, xb = bB, xc = cB;
                    const float2 ya = eaB, yb = ebB, yc = ecB;
                    int q3 = (q0 >= 0) ? pop() : -1;
                    if (q3 >= 0) issue(q3, aB, bB, cB, eaB, ebB, ecB);
                    compute(q1, xa, xb, xc, ya, yb, yc);
                    if (q0 < 0) break;
                    q1 = q3;
                }
            }
        }
    }

    // wave-direct store: window px (lr, lc..lc+3) = flat w*256 + 4*lane
    float4 o;
    o.x = acc0 * OSC; o.y = acc1 * OSC; o.z = acc2 * OSC; o.w = acc3 * OSC;
    float* obase = Out + (size_t)(b * COUT + co) * PIX + w * 256;
    reinterpret_cast<float4*>(obase)[lane] = o;
}

extern "C" void kernel_launch(void* const* d_in, const int* in_sizes, int n_in,
                              void* d_out, int out_size, void* d_ws, size_t ws_size,
                              hipStream_t stream) {
    (void)in_sizes; (void)n_in; (void)ws_size; (void)out_size;
    const float* V  = (const float*)d_in[0];   // (4,64,32,32)
    const float* Th = (const float*)d_in[1];   // (128,64,3,3)
    float* Out = (float*)d_out;                // (4,128,32,32)
    float* wg  = (float*)d_ws;                 // 4*64*4 floats = 4 KB
    void* args[] = { (void*)&V, (void*)&Th, (void*)&wg, (void*)&Out };
    hipLaunchCooperativeKernel((const void*)ekv_fused, dim3(4 * COUT),
                               dim3(256), args, 0, stream);
}

// Round 11
// 43.123 us; speedup vs baseline: 1.9501x; 1.9501x over previous
//
#include <hip/hip_runtime.h>

// EKV nonlinear conv2d, MI355X.
// out[b,co,h,w] = alpha * sum_{cin,i,j} sp((v-th)*inv)^2 - sp((v-th-0.1)*inv)^2
// log2-domain: e1 = 2^(v*s) * 2^(-th*s), e2 = e1*KF,
//   term = ln2^2 * (log2(1+e1)^2 - log2(1+e2)^2)
//
// v12 vs v11 (84us, REVERTED: grid.sync costs ~55us on 8 non-coherent XCDs
// -- stream-ordered kernel boundaries ARE the cheap cross-XCD sync) and
// v10 (24.1us): v3's decomposition bounds dispatch+harness overhead at
// ~4us, so v10's main is ~20us real vs ~2us of modeled issue -- exposed
// latency at only 8 waves/CU (grid 512 = 2 blocks/CU; the GRID caps
// occupancy). Restore wave count at v10's low overhead:
//  - block=(b,co,win), grid 2048, launch_bounds(256,8) -> 8 blocks/CU,
//    32 waves/CU (4x v10). v9's proven XCD swizzle (FETCH stayed
//    compulsory-1.55MB at this mapping in v7/v9).
//  - 4 waves share the window, rank-split the active-cin mask (popc O(1));
//    partials merged via 4KB LDS combine + one barrier.
//  - Body unchanged from v10: register/shuffle metadata (lane l owns cin l),
//    per-tap skip DELTA=5/S (worst-case skipped total 3.2e-4 < 7.47e-4
//    threshold), dead-row load elimination, 3-row register window + direct
//    edge scalars (pad before exp2), depth-2 ping-pong pipeline.

constexpr int CIN  = 64;
constexpr int COUT = 128;
constexpr int HW   = 32;
constexpr int PIX  = HW * HW;       // 1024

constexpr float S     = 19.235933878519512f;     // (1/0.075) * log2(e)
constexpr float KF    = 0.26359713811572677f;    // exp(-0.1/0.075)
constexpr float OSC   = 2.7025482032899376e-4f;  // alpha * ln2^2
constexpr float DELTA = 0.2599401f;              // 5/S rounded UP (conservative)

// ---- pre-kernel: wg[(b*CIN+cin)*4 + w] = max V over rows 8w-1..8w+8 (0 incl. halo)
__global__ __launch_bounds__(256)
void ekv_rowmax(const float* __restrict__ V, float* __restrict__ wg)
{
    const int t = threadIdx.x;
    const int plane = blockIdx.x;               // b*CIN + cin
    __shared__ float rmax[32];
    const float4 v4 = reinterpret_cast<const float4*>(V + (size_t)plane * PIX)[t];
    float m = fmaxf(fmaxf(v4.x, v4.y), fmaxf(v4.z, v4.w));
    m = fmaxf(m, __shfl_xor(m, 1));             // reduce 8 lanes of one row
    m = fmaxf(m, __shfl_xor(m, 2));
    m = fmaxf(m, __shfl_xor(m, 4));
    if ((t & 7) == 0) rmax[t >> 3] = m;
    __syncthreads();
    if (t < 4) {
        float wm = 0.0f;                        // halo pixels are v=0 -> e=1
        #pragma unroll
        for (int rr = 0; rr < 10; ++rr) {
            const int r = 8 * t - 1 + rr;
            if (r >= 0 && r < 32) wm = fmaxf(wm, rmax[r]);
        }
        wg[plane * 4 + t] = wm;
    }
}

// ---- main kernel: block = (b, co, win); 4 waves rank-split the active cin
__global__ __launch_bounds__(256, 8)
void ekv_main(const float* __restrict__ V, const float* __restrict__ Th,
              const float* __restrict__ wg, float* __restrict__ Out)
{
    const int t = threadIdx.x;
    // XCD-aware bijective swizzle (nwg=2048, 8 XCDs): XCD x gets a contiguous
    // 256-task chunk = one b, 64 consecutive co, all 4 windows -> L2-resident.
    const int task = ((blockIdx.x & 7) << 8) | (blockIdx.x >> 3);
    const int win  = task & 3;                  // 8-row window 0..3
    const int co   = (task >> 2) & (COUT - 1);
    const int b    = task >> 9;
    const int ph   = t >> 6;                    // wave = cin-split phase 0..3
    const int lane = t & 63;

    __shared__ float4 Cb[256];                  // cross-wave combine buffer

    const float* vbase = V  + (size_t)b  * CIN * PIX;
    const float* thp   = Th + (size_t)co * (CIN * 9);

    // ---- register prologue: lane l = cin l ----
    float th[9];
    #pragma unroll
    for (int k = 0; k < 9; ++k) th[k] = thp[lane * 9 + k];
    const float wgv = wg[(size_t)(b * CIN + lane) * 4 + win];
    const float lim = wgv + DELTA;
    unsigned tlm = 0u;                          // bit 3i+j: tap (i,j) live
    #pragma unroll
    for (int k = 0; k < 9; ++k) if (th[k] <= lim) tlm |= (1u << k);
    float q[9];
    #pragma unroll
    for (int k = 0; k < 9; ++k) q[k] = __builtin_amdgcn_exp2f(-th[k] * S);

    // rank-interleaved 4-way split of the active set (balanced across waves)
    const unsigned long long full = __ballot(tlm != 0u);
    const bool actv = (full >> lane) & 1ull;
    const int  rank = (int)__popcll(full & ((1ull << lane) - 1ull));
    unsigned long long mask = __ballot(actv && ((rank & 3) == ph));

    const int lr = lane >> 3;                   // 0..7
    const int lc = (lane & 7) * 4;              // 0..28
    const int r   = 8 * win + lr;               // own output/input row
    const int rm1 = (r - 1 < 0)  ? 0  : r - 1;  // clamped load rows
    const int rp1 = (r + 1 > 31) ? 31 : r + 1;
    const bool okA = (r - 1) >= 0;              // row above exists?
    const bool okC = (r + 1) <= 31;             // row below exists?
    const bool isL = (lane & 7) == 0;           // left image edge group
    const bool isR = (lane & 7) == 7;           // right image edge group
    const int  lcl = isL ? 0 : lc - 1;          // clamped edge-scalar cols
    const int  lcr = isR ? 31 : lc + 4;

    float acc0 = 0.f, acc1 = 0.f, acc2 = 0.f, acc3 = 0.f;

    auto pop = [&]() -> int {
        if (!mask) return -1;
        const int c = (int)__builtin_ctzll(mask); mask &= mask - 1; return c;
    };
    // load only live rows (liveness via wave-uniform shuffle of tlm)
    auto issue = [&](int cin, float4& A, float4& B, float4& C,
                     float2& eA, float2& eB, float2& eC) {
        const unsigned tc = (unsigned)__shfl((int)tlm, cin);
        const float* src = vbase + cin * PIX;
        if (tc & 7u) {
            const float* ra = src + rm1 * HW;
            A = *reinterpret_cast<const float4*>(ra + lc);
            eA.x = ra[lcl]; eA.y = ra[lcr];
        }
        if (tc & 56u) {
            const float* rb = src + r * HW;
            B = *reinterpret_cast<const float4*>(rb + lc);
            eB.x = rb[lcl]; eB.y = rb[lcr];
        }
        if (tc & 448u) {
            const float* rc = src + rp1 * HW;
            C = *reinterpret_cast<const float4*>(rc + lc);
            eC.x = rc[lcl]; eC.y = rc[lcr];
        }
    };
    // row -> 6 exp'd values; pad (v=0 -> e=1) selected BEFORE exp2
    auto rowv = [&](const float4& x, const float2& e, bool ok, float* vals) {
        vals[0] = __builtin_amdgcn_exp2f(((ok && !isL) ? e.x : 0.f) * S);
        vals[1] = __builtin_amdgcn_exp2f((ok ? x.x : 0.f) * S);
        vals[2] = __builtin_amdgcn_exp2f((ok ? x.y : 0.f) * S);
        vals[3] = __builtin_amdgcn_exp2f((ok ? x.z : 0.f) * S);
        vals[4] = __builtin_amdgcn_exp2f((ok ? x.w : 0.f) * S);
        vals[5] = __builtin_amdgcn_exp2f(((ok && !isR) ? e.y : 0.f) * S);
    };
    auto compute = [&](int cin, const float4& A, const float4& B, const float4& C,
                       const float2& eA, const float2& eB, const float2& eC) {
        const unsigned tc = (unsigned)__shfl((int)tlm, cin);
        float qc[9];
        #pragma unroll
        for (int k = 0; k < 9; ++k) qc[k] = __shfl(q[k], cin);
        #pragma unroll
        for (int i = 0; i < 3; ++i) {
            if (!((tc >> (3 * i)) & 7u)) continue;        // tap-row dead
            float vals[6];
            if      (i == 0) rowv(A, eA, okA, vals);
            else if (i == 1) rowv(B, eB, true, vals);
            else             rowv(C, eC, okC, vals);
            #pragma unroll
            for (int j = 0; j < 3; ++j) {
                if (!((tc >> (3 * i + j)) & 1u)) continue; // tap dead
                const float qa = qc[3 * i + j];
                const float qb = qa * KF;
                #pragma unroll
                for (int k = 0; k < 4; ++k) {
                    const float x1 = __builtin_fmaf(vals[k + j], qa, 1.0f);
                    const float x2 = __builtin_fmaf(vals[k + j], qb, 1.0f);
                    const float l1 = __builtin_amdgcn_logf(x1);   // log2
                    const float l2 = __builtin_amdgcn_logf(x2);
                    const float su = l1 + l2, di = l1 - l2;       // l1^2-l2^2
                    if      (k == 0) acc0 = __builtin_fmaf(su, di, acc0);
                    else if (k == 1) acc1 = __builtin_fmaf(su, di, acc1);
                    else if (k == 2) acc2 = __builtin_fmaf(su, di, acc2);
                    else             acc3 = __builtin_fmaf(su, di, acc3);
                }
            }
        }
    };

    // depth-2 pipeline, ping-pong register sets A/B (loads issued 2 planes ahead)
    {
        float4 aA = make_float4(0.f,0.f,0.f,0.f), bA = aA, cA = aA;
        float4 aB = aA, bB = aA, cB = aA;
        float2 eaA = make_float2(0.f,0.f), ebA = eaA, ecA = eaA;
        float2 eaB = eaA, ebB = eaA, ecB = eaA;
        int q0 = pop();
        if (q0 >= 0) {
            issue(q0, aA, bA, cA, eaA, ebA, ecA);
            int q1 = pop();
            if (q1 >= 0) issue(q1, aB, bB, cB, eaB, ebB, ecB);
            for (;;) {
                // EVEN: current plane q0 in set A; 2-ahead issued into dead A regs
                {
                    const float4 xa = aA, xb = bA, xc = cA;
                    const float2 ya = eaA, yb = ebA, yc = ecA;
                    int q2 = (q1 >= 0) ? pop() : -1;
                    if (q2 >= 0) issue(q2, aA, bA, cA, eaA, ebA, ecA);
                    compute(q0, xa, xb, xc, ya, yb, yc);
                    if (q1 < 0) break;
                    q0 = q2;
                }
                // ODD: current plane q1 in set B
                {
                    const float4 xa = aB, xb = bB, xc = cB;
                    const float2 ya = eaB, yb = ebB, yc = ecB;
                    int q3 = (q0 >= 0) ? pop() : -1;
                    if (q3 >= 0) issue(q3, aB, bB, cB, eaB, ebB, ecB);
                    compute(q1, xa, xb, xc, ya, yb, yc);
                    if (q0 < 0) break;
                    q1 = q3;
                }
            }
        }
    }

    // cross-wave combine: 4 partials per pixel group -> one float4 store
    Cb[t] = make_float4(acc0, acc1, acc2, acc3);
    __syncthreads();
    if (t < 64) {
        const float4 p0 = Cb[t];
        const float4 p1 = Cb[t + 64];
        const float4 p2 = Cb[t + 128];
        const float4 p3 = Cb[t + 192];
        float4 o;
        o.x = (p0.x + p1.x + p2.x + p3.x) * OSC;
        o.y = (p0.y + p1.y + p2.y + p3.y) * OSC;
        o.z = (p0.z + p1.z + p2.z + p3.z) * OSC;
        o.w = (p0.w + p1.w + p2.w + p3.w) * OSC;
        // window px (t>>3, (t&7)*4 ..+3) = flat win*256 + 4t
        float* obase = Out + (size_t)(b * COUT + co) * PIX + win * 256;
        reinterpret_cast<float4*>(obase)[t] = o;
    }
}

extern "C" void kernel_launch(void* const* d_in, const int* in_sizes, int n_in,
                              void* d_out, int out_size, void* d_ws, size_t ws_size,
                              hipStream_t stream) {
    (void)in_sizes; (void)n_in; (void)ws_size; (void)out_size;
    const float* V  = (const float*)d_in[0];   // (4,64,32,32)
    const float* Th = (const float*)d_in[1];   // (128,64,3,3)
    float* Out = (float*)d_out;                // (4,128,32,32)
    float* wg  = (float*)d_ws;                 // 4*64*4 floats = 4 KB
    ekv_rowmax<<<dim3(4 * CIN), dim3(256), 0, stream>>>(V, wg);
    ekv_main<<<dim3(4 * COUT * 4), dim3(256), 0, stream>>>(V, Th, wg, Out);
}

// Round 12
// 25.577 us; speedup vs baseline: 3.2879x; 1.6860x over previous
//
#include <hip/hip_runtime.h>

// EKV nonlinear conv2d, MI355X.
// out[b,co,h,w] = alpha * sum_{cin,i,j} sp((v-th)*inv)^2 - sp((v-th-0.1)*inv)^2
// log2-domain: e1 = 2^(v*s) * 2^(-th*s), e2 = e1*KF,
//   term = ln2^2 * (log2(1+e1)^2 - log2(1+e2)^2)
//
// v13 vs v12 (43us, REVERTED: 2048 blocks quadrupled the per-block prologue
// (576 theta loads + 576 exp2 + chain) and re-added the combine barrier) and
// v10 (24.1us best): the cost is metadata, not math. Make metadata ~free at
// v10's proven 512-block shape:
//  - thmin[co,cin] precomputed (32KB in d_ws) by extra blocks fused into the
//    rowmax pre-kernel launch. Main prologue: 2 coalesced loads + 1 ballot
//    (was 9 loads + 9 exp2 + mask build per lane).
//  - Per-plane metadata via UNIFORM loads: cin = ctz(ballot) is wave-uniform,
//    so th[cin][0..8] and wgv[cin] come from scalar/broadcast loads --
//    replaces v10's 10 ds_bpermute per plane. Tap test = th <= wgv_c + DELTA
//    directly; q = exp2(-th*S) computed ONLY for live taps (~1.2/plane).
//  - All 3 rows always loaded (removes th->row dependency; dead rows still
//    skip their exp2/taps at compute). Depth-2 ping-pong kept.
// Skip semantics identical to v10 (same DELTA, same inequality) -> same
// absmax 7.63e-6. Worst-case skipped-term total 3.2e-4 < 7.47e-4 threshold.

constexpr int CIN  = 64;
constexpr int COUT = 128;
constexpr int HW   = 32;
constexpr int PIX  = HW * HW;       // 1024

constexpr float S     = 19.235933878519512f;     // (1/0.075) * log2(e)
constexpr float KF    = 0.26359713811572677f;    // exp(-0.1/0.075)
constexpr float OSC   = 2.7025482032899376e-4f;  // alpha * ln2^2
constexpr float DELTA = 0.2599401f;              // 5/S rounded UP (conservative)

// ---- pre-kernel: blocks 0..255 -> wg window-max table; 256..287 -> thmin
__global__ __launch_bounds__(256)
void ekv_pre(const float* __restrict__ V, const float* __restrict__ Th,
             float* __restrict__ wg, float* __restrict__ thmin)
{
    const int t = threadIdx.x;
    const int g = blockIdx.x;
    if (g < 4 * CIN) {
        __shared__ float rmax[32];
        const float4 v4 = reinterpret_cast<const float4*>(V + (size_t)g * PIX)[t];
        float m = fmaxf(fmaxf(v4.x, v4.y), fmaxf(v4.z, v4.w));
        m = fmaxf(m, __shfl_xor(m, 1));         // reduce 8 lanes of one row
        m = fmaxf(m, __shfl_xor(m, 2));
        m = fmaxf(m, __shfl_xor(m, 4));
        if ((t & 7) == 0) rmax[t >> 3] = m;
        __syncthreads();
        if (t < 4) {
            float wm = 0.0f;                    // halo pixels are v=0 -> e=1
            #pragma unroll
            for (int rr = 0; rr < 10; ++rr) {
                const int r = 8 * t - 1 + rr;
                if (r >= 0 && r < 32) wm = fmaxf(wm, rmax[r]);
            }
            wg[g * 4 + t] = wm;                 // wg[(b*CIN+cin)*4 + w]
        }
    } else {
        // thmin[co*64+cin] = min of the 9 taps (8192 entries)
        const int idx = (g - 4 * CIN) * 256 + t;
        const float* p = Th + (size_t)idx * 9;
        float m = p[0];
        #pragma unroll
        for (int k = 1; k < 9; ++k) m = fminf(m, p[k]);
        thmin[idx] = m;
    }
}

// ---- main kernel: block = (b, co); wave w owns 8-row window w
__global__ __launch_bounds__(256, 4)
void ekv_main(const float* __restrict__ V, const float* __restrict__ Th,
              const float* __restrict__ wg, const float* __restrict__ thmin,
              float* __restrict__ Out)
{
    const int t = threadIdx.x;
    // XCD-aware bijective swizzle (nwg=512, 8 XCDs): XCD x gets a contiguous
    // 64-task chunk (one b, 64 consecutive co) -> L2-resident working set.
    const int task = ((blockIdx.x & 7) << 6) | (blockIdx.x >> 3);
    const int co   = task & (COUT - 1);
    const int b    = task >> 7;
    const int w    = t >> 6;                    // wave = window 0..3
    const int lane = t & 63;

    const float* vbase = V  + (size_t)b  * CIN * PIX;
    const float* thp   = Th + (size_t)co * (CIN * 9);
    const float* wgb   = wg + (size_t)b * CIN * 4;

    // ---- prologue: 2 coalesced loads + ballot ----
    const float tmn = thmin[co * CIN + lane];   // lane l = cin l
    const float wgv = wgb[lane * 4 + w];
    unsigned long long mask = __ballot(tmn <= wgv + DELTA);

    const int lr = lane >> 3;                   // 0..7
    const int lc = (lane & 7) * 4;              // 0..28
    const int r   = 8 * w + lr;                 // own output/input row
    const int rm1 = (r - 1 < 0)  ? 0  : r - 1;  // clamped load rows
    const int rp1 = (r + 1 > 31) ? 31 : r + 1;
    const bool okA = (r - 1) >= 0;              // row above exists?
    const bool okC = (r + 1) <= 31;             // row below exists?
    const bool isL = (lane & 7) == 0;           // left image edge group
    const bool isR = (lane & 7) == 7;           // right image edge group
    const int  lcl = isL ? 0 : lc - 1;          // clamped edge-scalar cols
    const int  lcr = isR ? 31 : lc + 4;

    float acc0 = 0.f, acc1 = 0.f, acc2 = 0.f, acc3 = 0.f;

    struct Pl {                                 // per-plane pipeline payload
        float4 A, B, C;                         // 3 rows, 4 center px each
        float2 eA, eB, eC;                      // (left,right) edge scalars
        float  th[9];                           // taps (uniform -> scalar regs)
        float  wgc;                             // window vmax for this cin
    };

    auto pop = [&]() -> int {
        if (!mask) return -1;
        const int c = (int)__builtin_ctzll(mask); mask &= mask - 1; return c;
    };
    auto issue = [&](int cin, Pl& p) {
        const float* src = vbase + cin * PIX;
        const float* ra = src + rm1 * HW;
        const float* rb = src + r   * HW;
        const float* rc = src + rp1 * HW;
        p.A = *reinterpret_cast<const float4*>(ra + lc);
        p.B = *reinterpret_cast<const float4*>(rb + lc);
        p.C = *reinterpret_cast<const float4*>(rc + lc);
        p.eA.x = ra[lcl]; p.eA.y = ra[lcr];
        p.eB.x = rb[lcl]; p.eB.y = rb[lcr];
        p.eC.x = rc[lcl]; p.eC.y = rc[lcr];
        const float* tp = thp + cin * 9;        // uniform address -> s_load
        #pragma unroll
        for (int k = 0; k < 9; ++k) p.th[k] = tp[k];
        p.wgc = wgb[cin * 4 + w];               // uniform
    };
    // row -> 6 exp'd values; pad (v=0 -> e=1) selected BEFORE exp2
    auto rowv = [&](const float4& x, const float2& e, bool ok, float* vals) {
        vals[0] = __builtin_amdgcn_exp2f(((ok && !isL) ? e.x : 0.f) * S);
        vals[1] = __builtin_amdgcn_exp2f((ok ? x.x : 0.f) * S);
        vals[2] = __builtin_amdgcn_exp2f((ok ? x.y : 0.f) * S);
        vals[3] = __builtin_amdgcn_exp2f((ok ? x.z : 0.f) * S);
        vals[4] = __builtin_amdgcn_exp2f((ok ? x.w : 0.f) * S);
        vals[5] = __builtin_amdgcn_exp2f(((ok && !isR) ? e.y : 0.f) * S);
    };
    auto compute = [&](const Pl& p) {
        const float lim = p.wgc + DELTA;        // uniform
        #pragma unroll
        for (int i = 0; i < 3; ++i) {
            const float t0 = p.th[3 * i], t1 = p.th[3 * i + 1], t2 = p.th[3 * i + 2];
            if (fminf(fminf(t0, t1), t2) > lim) continue;   // row dead (uniform)
            float vals[6];
            if      (i == 0) rowv(p.A, p.eA, okA, vals);
            else if (i == 1) rowv(p.B, p.eB, true, vals);
            else             rowv(p.C, p.eC, okC, vals);
            #pragma unroll
            for (int j = 0; j < 3; ++j) {
                const float tj = (j == 0) ? t0 : (j == 1) ? t1 : t2;
                if (tj > lim) continue;                     // tap dead (uniform)
                const float qa = __builtin_amdgcn_exp2f(-tj * S);
                const float qb = qa * KF;
                #pragma unroll
                for (int k = 0; k < 4; ++k) {
                    const float x1 = __builtin_fmaf(vals[k + j], qa, 1.0f);
                    const float x2 = __builtin_fmaf(vals[k + j], qb, 1.0f);
                    const float l1 = __builtin_amdgcn_logf(x1);   // log2
                    const float l2 = __builtin_amdgcn_logf(x2);
                    const float su = l1 + l2, di = l1 - l2;       // l1^2-l2^2
                    if      (k == 0) acc0 = __builtin_fmaf(su, di, acc0);
                    else if (k == 1) acc1 = __builtin_fmaf(su, di, acc1);
                    else if (k == 2) acc2 = __builtin_fmaf(su, di, acc2);
                    else             acc3 = __builtin_fmaf(su, di, acc3);
                }
            }
        }
    };

    // depth-2 pipeline, ping-pong payloads A/B (loads issued 2 planes ahead)
    {
        Pl plA, plB;
        int q0 = pop();
        if (q0 >= 0) {
            issue(q0, plA);
            int q1 = pop();
            if (q1 >= 0) issue(q1, plB);
            for (;;) {
                // EVEN: current plane q0 in plA; 2-ahead issued into dead plA
                {
                    const Pl cur = plA;
                    int q2 = (q1 >= 0) ? pop() : -1;
                    if (q2 >= 0) issue(q2, plA);
                    compute(cur);
                    if (q1 < 0) break;
                    q0 = q2;
                }
                // ODD: current plane q1 in plB
                {
                    const Pl cur = plB;
                    int q3 = (q0 >= 0) ? pop() : -1;
                    if (q3 >= 0) issue(q3, plB);
                    compute(cur);
                    if (q0 < 0) break;
                    q1 = q3;
                }
            }
        }
    }

    // wave-direct store: window px (lr, lc..lc+3) = flat w*256 + 4*lane
    float4 o;
    o.x = acc0 * OSC; o.y = acc1 * OSC; o.z = acc2 * OSC; o.w = acc3 * OSC;
    float* obase = Out + (size_t)(b * COUT + co) * PIX + w * 256;
    reinterpret_cast<float4*>(obase)[lane] = o;
}

extern "C" void kernel_launch(void* const* d_in, const int* in_sizes, int n_in,
                              void* d_out, int out_size, void* d_ws, size_t ws_size,
                              hipStream_t stream) {
    (void)in_sizes; (void)n_in; (void)ws_size; (void)out_size;
    const float* V  = (const float*)d_in[0];   // (4,64,32,32)
    const float* Th = (const float*)d_in[1];   // (128,64,3,3)
    float* Out = (float*)d_out;                // (4,128,32,32)
    float* wg    = (float*)d_ws;               // 4*64*4 floats   (4 KB)
    float* thmin = wg + 4 * CIN * 4;           // 128*64 floats  (32 KB)
    ekv_pre <<<dim3(4 * CIN + 32), dim3(256), 0, stream>>>(V, Th, wg, thmin);
    ekv_main<<<dim3(4 * COUT),     dim3(256), 0, stream>>>(V, Th, wg, thmin, Out);
}

// Round 13
// 23.703 us; speedup vs baseline: 3.5479x; 1.0791x over previous
//
#include <hip/hip_runtime.h>

// EKV nonlinear conv2d, MI355X — FINAL (revert to measured-best v10, 24.1us).
// out[b,co,h,w] = alpha * sum_{cin,i,j} sp((v-th)*inv)^2 - sp((v-th-0.1)*inv)^2
// log2-domain: e1 = 2^(v*s) * 2^(-th*s), e2 = e1*KF,
//   term = ln2^2 * (log2(1+e1)^2 - log2(1+e2)^2)
//
// Session ladder: 96.4 (baseline) -> 78.5 (block sparsity skip) -> 42.6
// (barrier-free per-wave LDS) -> 45.8 (zero-LDS register window) -> 29.2
// (per-tap skip) -> 25.7 (queue + dead-row loads) -> 24.1 (THIS: shuffle
// metadata, no LDS/no barriers, grid 512). Rejected by measurement: v11
// grid.sync fusion (84us: cross-XCD coop sync ~55us), v12 32 waves/CU
// (43us: 4x per-block prologue), v13 uniform-load metadata (25.6us:
// serial-chain latency). Structural floor ~24us = two dispatches + rowmax
// + prologue chains; no roofline near (HBM ~1%, VALU <50%, conflicts 0).
//
// Key mechanics:
//  - rowmax pre-kernel -> wg[(b*CIN+cin)*4+w]: window max of V (halo=0).
//  - Main: block=(b,co), wave w owns 8-row window w; lane l owns cin l's
//    metadata in REGISTERS (9 theta, tap-live mask tlm, q[k]=exp2(-th*S));
//    per-plane broadcast via __shfl. Zero LDS, zero barriers.
//  - Per-tap skip at DELTA=5/S: tap live iff th <= window_vmax + DELTA.
//    Worst-case skipped-term total 576*OSC*(1.443*2^-5)^2 ~ 3.2e-4 <
//    7.47e-4 threshold (measured absmax 7.63e-6).
//  - Dead-row load elimination via tlm row bits; 3-row register window +
//    direct edge scalar loads (pad v=0 -> e=1 selected BEFORE exp2).
//  - Depth-2 ping-pong pipeline (loads 2 planes ahead).
//  - XCD-bijective swizzle (nwg=512): each XCD owns one b + 64 consecutive
//    co -> L2-resident; FETCH stays at compulsory ~1.6MB.

constexpr int CIN  = 64;
constexpr int COUT = 128;
constexpr int HW   = 32;
constexpr int PIX  = HW * HW;       // 1024

constexpr float S     = 19.235933878519512f;     // (1/0.075) * log2(e)
constexpr float KF    = 0.26359713811572677f;    // exp(-0.1/0.075)
constexpr float OSC   = 2.7025482032899376e-4f;  // alpha * ln2^2
constexpr float DELTA = 0.2599401f;              // 5/S rounded UP (conservative)

// ---- pre-kernel: wg[(b*CIN+cin)*4 + w] = max V over rows 8w-1..8w+8 (0 incl. halo)
__global__ __launch_bounds__(256)
void ekv_rowmax(const float* __restrict__ V, float* __restrict__ wg)
{
    const int t = threadIdx.x;
    const int plane = blockIdx.x;               // b*CIN + cin
    __shared__ float rmax[32];
    const float4 v4 = reinterpret_cast<const float4*>(V + (size_t)plane * PIX)[t];
    float m = fmaxf(fmaxf(v4.x, v4.y), fmaxf(v4.z, v4.w));
    m = fmaxf(m, __shfl_xor(m, 1));             // reduce 8 lanes of one row
    m = fmaxf(m, __shfl_xor(m, 2));
    m = fmaxf(m, __shfl_xor(m, 4));
    if ((t & 7) == 0) rmax[t >> 3] = m;
    __syncthreads();
    if (t < 4) {
        float wm = 0.0f;                        // halo pixels are v=0 -> e=1
        #pragma unroll
        for (int rr = 0; rr < 10; ++rr) {
            const int r = 8 * t - 1 + rr;
            if (r >= 0 && r < 32) wm = fmaxf(wm, rmax[r]);
        }
        wg[plane * 4 + t] = wm;
    }
}

// ---- main kernel: block = (b, co); wave w owns 8-row window w; lane l owns
// cin l's metadata. No LDS, no barriers.
__global__ __launch_bounds__(256, 4)
void ekv_main(const float* __restrict__ V, const float* __restrict__ Th,
              const float* __restrict__ wg, float* __restrict__ Out)
{
    const int t = threadIdx.x;
    // XCD-aware bijective swizzle (nwg=512, 8 XCDs): XCD x gets a contiguous
    // 64-task chunk (one b, 64 consecutive co) -> L2-resident working set.
    const int task = ((blockIdx.x & 7) << 6) | (blockIdx.x >> 3);
    const int co   = task & (COUT - 1);
    const int b    = task >> 7;
    const int w    = t >> 6;                    // wave = window 0..3
    const int lane = t & 63;

    const float* vbase = V  + (size_t)b  * CIN * PIX;
    const float* thp   = Th + (size_t)co * (CIN * 9);

    // ---- register prologue: lane l = cin l ----
    float th[9];
    #pragma unroll
    for (int k = 0; k < 9; ++k) th[k] = thp[lane * 9 + k];
    const float wgv = wg[(size_t)(b * CIN + lane) * 4 + w];
    const float lim = wgv + DELTA;
    unsigned tlm = 0u;                          // bit 3i+j: tap (i,j) live
    #pragma unroll
    for (int k = 0; k < 9; ++k) if (th[k] <= lim) tlm |= (1u << k);
    float q[9];
    #pragma unroll
    for (int k = 0; k < 9; ++k) q[k] = __builtin_amdgcn_exp2f(-th[k] * S);
    unsigned long long mask = __ballot(tlm != 0u);   // this wave's active cin

    const int lr = lane >> 3;                   // 0..7
    const int lc = (lane & 7) * 4;              // 0..28
    const int r   = 8 * w + lr;                 // own output/input row
    const int rm1 = (r - 1 < 0)  ? 0  : r - 1;  // clamped load rows
    const int rp1 = (r + 1 > 31) ? 31 : r + 1;
    const bool okA = (r - 1) >= 0;              // row above exists?
    const bool okC = (r + 1) <= 31;             // row below exists?
    const bool isL = (lane & 7) == 0;           // left image edge group
    const bool isR = (lane & 7) == 7;           // right image edge group
    const int  lcl = isL ? 0 : lc - 1;          // clamped edge-scalar cols
    const int  lcr = isR ? 31 : lc + 4;

    float acc0 = 0.f, acc1 = 0.f, acc2 = 0.f, acc3 = 0.f;

    auto pop = [&]() -> int {
        if (!mask) return -1;
        const int c = (int)__builtin_ctzll(mask); mask &= mask - 1; return c;
    };
    // load only live rows (liveness via wave-uniform shuffle of tlm)
    auto issue = [&](int cin, float4& A, float4& B, float4& C,
                     float2& eA, float2& eB, float2& eC) {
        const unsigned tc = (unsigned)__shfl((int)tlm, cin);
        const float* src = vbase + cin * PIX;
        if (tc & 7u) {
            const float* ra = src + rm1 * HW;
            A = *reinterpret_cast<const float4*>(ra + lc);
            eA.x = ra[lcl]; eA.y = ra[lcr];
        }
        if (tc & 56u) {
            const float* rb = src + r * HW;
            B = *reinterpret_cast<const float4*>(rb + lc);
            eB.x = rb[lcl]; eB.y = rb[lcr];
        }
        if (tc & 448u) {
            const float* rc = src + rp1 * HW;
            C = *reinterpret_cast<const float4*>(rc + lc);
            eC.x = rc[lcl]; eC.y = rc[lcr];
        }
    };
    // row -> 6 exp'd values; pad (v=0 -> e=1) selected BEFORE exp2
    auto rowv = [&](const float4& x, const float2& e, bool ok, float* vals) {
        vals[0] = __builtin_amdgcn_exp2f(((ok && !isL) ? e.x : 0.f) * S);
        vals[1] = __builtin_amdgcn_exp2f((ok ? x.x : 0.f) * S);
        vals[2] = __builtin_amdgcn_exp2f((ok ? x.y : 0.f) * S);
        vals[3] = __builtin_amdgcn_exp2f((ok ? x.z : 0.f) * S);
        vals[4] = __builtin_amdgcn_exp2f((ok ? x.w : 0.f) * S);
        vals[5] = __builtin_amdgcn_exp2f(((ok && !isR) ? e.y : 0.f) * S);
    };
    auto compute = [&](int cin, const float4& A, const float4& B, const float4& C,
                       const float2& eA, const float2& eB, const float2& eC) {
        const unsigned tc = (unsigned)__shfl((int)tlm, cin);
        float qc[9];
        #pragma unroll
        for (int k = 0; k < 9; ++k) qc[k] = __shfl(q[k], cin);
        #pragma unroll
        for (int i = 0; i < 3; ++i) {
            if (!((tc >> (3 * i)) & 7u)) continue;        // tap-row dead
            float vals[6];
            if      (i == 0) rowv(A, eA, okA, vals);
            else if (i == 1) rowv(B, eB, true, vals);
            else             rowv(C, eC, okC, vals);
            #pragma unroll
            for (int j = 0; j < 3; ++j) {
                if (!((tc >> (3 * i + j)) & 1u)) continue; // tap dead
                const float qa = qc[3 * i + j];
                const float qb = qa * KF;
                #pragma unroll
                for (int k = 0; k < 4; ++k) {
                    const float x1 = __builtin_fmaf(vals[k + j], qa, 1.0f);
                    const float x2 = __builtin_fmaf(vals[k + j], qb, 1.0f);
                    const float l1 = __builtin_amdgcn_logf(x1);   // log2
                    const float l2 = __builtin_amdgcn_logf(x2);
                    const float su = l1 + l2, di = l1 - l2;       // l1^2-l2^2
                    if      (k == 0) acc0 = __builtin_fmaf(su, di, acc0);
                    else if (k == 1) acc1 = __builtin_fmaf(su, di, acc1);
                    else if (k == 2) acc2 = __builtin_fmaf(su, di, acc2);
                    else             acc3 = __builtin_fmaf(su, di, acc3);
                }
            }
        }
    };

    // depth-2 pipeline, ping-pong register sets A/B (loads issued 2 planes ahead)
    {
        float4 aA = make_float4(0.f,0.f,0.f,0.f), bA = aA, cA = aA;
        float4 aB = aA, bB = aA, cB = aA;
        float2 eaA = make_float2(0.f,0.f), ebA = eaA, ecA = eaA;
        float2 eaB = eaA, ebB = eaA, ecB = eaA;
        int q0 = pop();
        if (q0 >= 0) {
            issue(q0, aA, bA, cA, eaA, ebA, ecA);
            int q1 = pop();
            if (q1 >= 0) issue(q1, aB, bB, cB, eaB, ebB, ecB);
            for (;;) {
                // EVEN: current plane q0 in set A; 2-ahead issued into dead A regs
                {
                    const float4 xa = aA, xb = bA, xc = cA;
                    const float2 ya = eaA, yb = ebA, yc = ecA;
                    int q2 = (q1 >= 0) ? pop() : -1;
                    if (q2 >= 0) issue(q2, aA, bA, cA, eaA, ebA, ecA);
                    compute(q0, xa, xb, xc, ya, yb, yc);
                    if (q1 < 0) break;
                    q0 = q2;
                }
                // ODD: current plane q1 in set B
                {
                    const float4 xa = aB, xb = bB, xc = cB;
                    const float2 ya = eaB, yb = ebB, yc = ecB;
                    int q3 = (q0 >= 0) ? pop() : -1;
                    if (q3 >= 0) issue(q3, aB, bB, cB, eaB, ebB, ecB);
                    compute(q1, xa, xb, xc, ya, yb, yc);
                    if (q0 < 0) break;
                    q1 = q3;
                }
            }
        }
    }

    // wave-direct store: window px (lr, lc..lc+3) = flat w*256 + 4*lane
    float4 o;
    o.x = acc0 * OSC; o.y = acc1 * OSC; o.z = acc2 * OSC; o.w = acc3 * OSC;
    float* obase = Out + (size_t)(b * COUT + co) * PIX + w * 256;
    reinterpret_cast<float4*>(obase)[lane] = o;
}

extern "C" void kernel_launch(void* const* d_in, const int* in_sizes, int n_in,
                              void* d_out, int out_size, void* d_ws, size_t ws_size,
                              hipStream_t stream) {
    (void)in_sizes; (void)n_in; (void)ws_size; (void)out_size;
    const float* V  = (const float*)d_in[0];   // (4,64,32,32)
    const float* Th = (const float*)d_in[1];   // (128,64,3,3)
    float* Out = (float*)d_out;                // (4,128,32,32)
    float* wg  = (float*)d_ws;                 // 4*64*4 floats = 4 KB
    ekv_rowmax<<<dim3(4 * CIN), dim3(256), 0, stream>>>(V, wg);
    ekv_main<<<dim3(4 * COUT), dim3(256), 0, stream>>>(V, Th, wg, Out);
}